// Round 1
// baseline (561.450 us; speedup 1.0000x reference)
//
#include <hip/hip_runtime.h>
#include <hip/hip_bf16.h>

typedef __bf16 bf16;
typedef __attribute__((ext_vector_type(4))) __bf16 bf16x4;
typedef __attribute__((ext_vector_type(8))) __bf16 bf16x8;
typedef __attribute__((ext_vector_type(4))) float f32x4;

#define D_IN  4096
#define D_OUT 4096
#define M_TOT 8192

// ---- async 16B global->LDS (wave-uniform base + lane*16 dest semantics) ----
__device__ __forceinline__ void async16(const void* g, void* l) {
  __builtin_amdgcn_global_load_lds(
      (__attribute__((address_space(1))) void*)g,
      (__attribute__((address_space(3))) void*)l,
      16, 0, 0);
}

// ---- kernel 1: x fp32 -> bf16 ----
__global__ void cvt_x_kernel(const float* __restrict__ x, bf16* __restrict__ xb) {
  int i = blockIdx.x * 256 + threadIdx.x;   // one float4 per thread, exact grid
  float4 v = ((const float4*)x)[i];
  bf16x4 o;
  o[0] = (bf16)v.x; o[1] = (bf16)v.y; o[2] = (bf16)v.z; o[3] = (bf16)v.w;
  ((bf16x4*)xb)[i] = o;
}

// ---- kernel 2: per-row L2 norm (fp64 accum) + quantize to bf16 integer q ----
// q = rint(clip(W/(norm+1e-8), -1, 1) / scale),  scale = (float)(1/127)
// s[row] = norm * scale   (folds denorm and dequant scale)
__global__ void quant_w_kernel(const float* __restrict__ W, bf16* __restrict__ qb,
                               float* __restrict__ s) {
  const int row = blockIdx.x;
  const int t = threadIdx.x;
  const float* wr = W + (size_t)row * D_IN;

  float4 v[4];
  double ss = 0.0;
#pragma unroll
  for (int j = 0; j < 4; j++) {
    v[j] = ((const float4*)wr)[j * 256 + t];
    ss += (double)v[j].x * v[j].x + (double)v[j].y * v[j].y +
          (double)v[j].z * v[j].z + (double)v[j].w * v[j].w;
  }
  // wave reduce (64 lanes) then cross-wave via LDS
#pragma unroll
  for (int off = 32; off; off >>= 1) ss += __shfl_down(ss, off);
  __shared__ double red[4];
  __shared__ float shn;
  const int lane = t & 63, wave = t >> 6;
  if (lane == 0) red[wave] = ss;
  __syncthreads();
  if (t == 0) {
    double tot = red[0] + red[1] + red[2] + red[3];
    float nrm = (float)sqrt(tot);
    shn = nrm;
    s[row] = nrm * (float)(1.0 / 127.0);
  }
  __syncthreads();

  const float den = shn + 1e-8f;
  const float scale = (float)(1.0 / 127.0);
  bf16* qr = qb + (size_t)row * D_IN;
#pragma unroll
  for (int j = 0; j < 4; j++) {
    bf16x4 o;
    float e[4] = {v[j].x, v[j].y, v[j].z, v[j].w};
#pragma unroll
    for (int c = 0; c < 4; c++) {
      float wn = e[c] / den;
      wn = fminf(1.0f, fmaxf(-1.0f, wn));
      o[c] = (bf16)rintf(wn / scale);   // integer in [-127,127], exact in bf16
    }
    ((bf16x4*)qr)[j * 256 + t] = o;
  }
}

// ---- kernel 3: bf16 GEMM, C[M,N] = A[M,K] @ B[N,K]^T, epilogue *s[n]+bias[n]
// 128x128 block tile, BK=32, 256 threads = 4 waves in 2x2, each wave 64x64
// (4x4 grid of 16x16x32 MFMAs). global_load_lds width-16 staging (m97 shape).
__global__ void gemm_bt_kernel(const bf16* __restrict__ A, const bf16* __restrict__ B,
                               const float* __restrict__ s, const float* __restrict__ bias,
                               float* __restrict__ C) {
  __shared__ __align__(16) bf16 lds_a[128 * 32];
  __shared__ __align__(16) bf16 lds_b[128 * 32];

  const int t = threadIdx.x;
  const int lane = t & 63;
  const int wave = t >> 6;
  const int wm = wave >> 1, wn = wave & 1;
  const int m0 = blockIdx.y * 128;
  const int n0 = blockIdx.x * 128;

  // staging: thread t loads 8 bf16 (16B); rows 0..63 round 0, 64..127 round 1
  const int r_a = t >> 2;            // row within tile (round 0)
  const int kk = (t & 3) * 8;        // k offset within BK
  const bf16* gA = A + (size_t)(m0 + r_a) * D_IN + kk;
  const bf16* gB = B + (size_t)(n0 + r_a) * D_IN + kk;
  bf16* lA = lds_a + t * 8;          // byte offset t*16; wave-uniform base + lane*16
  bf16* lB = lds_b + t * 8;
  const size_t rstride = (size_t)64 * D_IN;  // +64 rows for round 1

  // fragment addressing: A[m = lane&15][k = (lane>>4)*8 + j]
  const int ml = lane & 15;
  const int kq = (lane >> 4) * 8;
  const bf16* ra = lds_a + (wm * 64 + ml) * 32 + kq;
  const bf16* rb = lds_b + (wn * 64 + ml) * 32 + kq;

  f32x4 acc[4][4];
#pragma unroll
  for (int i = 0; i < 4; i++)
#pragma unroll
    for (int j = 0; j < 4; j++) acc[i][j] = (f32x4)0.0f;

  for (int k0 = 0; k0 < D_IN; k0 += 32) {
    async16(gA, lA);
    async16(gA + rstride, lA + 2048);
    async16(gB, lB);
    async16(gB + rstride, lB + 2048);
    gA += 32; gB += 32;
    __syncthreads();   // drains vmcnt -> LDS tiles ready

    bf16x8 af[4], bfr[4];
#pragma unroll
    for (int i = 0; i < 4; i++) {
      af[i]  = *(const bf16x8*)(ra + i * 16 * 32);
      bfr[i] = *(const bf16x8*)(rb + i * 16 * 32);
    }
#pragma unroll
    for (int mi = 0; mi < 4; mi++)
#pragma unroll
      for (int ni = 0; ni < 4; ni++)
        acc[mi][ni] = __builtin_amdgcn_mfma_f32_16x16x32_bf16(af[mi], bfr[ni], acc[mi][ni], 0, 0, 0);
    __syncthreads();   // before next staging overwrites LDS
  }

  // epilogue: D col = lane&15 (n), row = (lane>>4)*4 + reg (m)
#pragma unroll
  for (int ni = 0; ni < 4; ni++) {
    const int col = n0 + wn * 64 + ni * 16 + ml;
    const float sc = s[col];
    const float bs = bias[col];
#pragma unroll
    for (int mi = 0; mi < 4; mi++) {
      const int row = m0 + wm * 64 + mi * 16 + (lane >> 4) * 4;
#pragma unroll
      for (int r = 0; r < 4; r++)
        C[(size_t)(row + r) * D_OUT + col] = acc[mi][ni][r] * sc + bs;
    }
  }
}

extern "C" void kernel_launch(void* const* d_in, const int* in_sizes, int n_in,
                              void* d_out, int out_size, void* d_ws, size_t ws_size,
                              hipStream_t stream) {
  const float* x    = (const float*)d_in[0];   // [4,2048,4096]
  const float* W    = (const float*)d_in[1];   // [4096,4096]
  const float* bias = (const float*)d_in[2];   // [4096]
  float* out = (float*)d_out;                  // [4,2048,4096]

  char* ws = (char*)d_ws;
  bf16*  xb = (bf16*)ws;                                          // 64 MiB
  bf16*  qb = (bf16*)(ws + (size_t)M_TOT * D_IN * 2);             // 32 MiB
  float* s  = (float*)(ws + (size_t)M_TOT * D_IN * 2 + (size_t)D_OUT * D_IN * 2);

  cvt_x_kernel<<<(M_TOT * D_IN / 4) / 256, 256, 0, stream>>>(x, xb);
  quant_w_kernel<<<D_OUT, 256, 0, stream>>>(W, qb, s);
  dim3 grid(D_OUT / 128, M_TOT / 128);   // (32, 64)
  gemm_bt_kernel<<<grid, 256, 0, stream>>>(xb, qb, s, bias, out);
}

// Round 2
// 420.309 us; speedup vs baseline: 1.3358x; 1.3358x over previous
//
#include <hip/hip_runtime.h>
#include <hip/hip_bf16.h>

typedef __attribute__((ext_vector_type(4))) int i32x4;

#define D_IN  4096
#define D_OUT 4096
#define M_TOT 8192

// ---- async 16B global->LDS (wave-uniform base + lane*16 dest semantics) ----
__device__ __forceinline__ void async16(const void* g, void* l) {
  __builtin_amdgcn_global_load_lds(
      (__attribute__((address_space(1))) void*)g,
      (__attribute__((address_space(3))) void*)l,
      16, 0, 0);
}

__device__ __forceinline__ int pack4(float a, float b, float c, float d, float s) {
  int q0 = (int)rintf(a * s) & 255;
  int q1 = (int)rintf(b * s) & 255;
  int q2 = (int)rintf(c * s) & 255;
  int q3 = (int)rintf(d * s) & 255;
  return q0 | (q1 << 8) | (q2 << 16) | (q3 << 24);
}

// ---- kernel 1: per-row absmax quantize x -> int8, sx[row] = rowmax/127 ----
__global__ void quant_x_kernel(const float* __restrict__ x, int4* __restrict__ xq,
                               float* __restrict__ sx) {
  const int row = blockIdx.x;
  const int t = threadIdx.x;
  const float* xr = x + (size_t)row * D_IN;

  float4 v[4];
  float mx = 0.f;
#pragma unroll
  for (int j = 0; j < 4; j++) {
    v[j] = ((const float4*)xr)[t * 4 + j];   // elements [16t, 16t+16)
    mx = fmaxf(mx, fmaxf(fmaxf(fabsf(v[j].x), fabsf(v[j].y)),
                         fmaxf(fabsf(v[j].z), fabsf(v[j].w))));
  }
#pragma unroll
  for (int off = 32; off; off >>= 1) mx = fmaxf(mx, __shfl_down(mx, off));
  __shared__ float red[4];
  __shared__ float smx;
  if ((t & 63) == 0) red[t >> 6] = mx;
  __syncthreads();
  if (t == 0) {
    float m = fmaxf(fmaxf(red[0], red[1]), fmaxf(red[2], red[3]));
    smx = m;
    sx[row] = m * (1.0f / 127.0f);
  }
  __syncthreads();

  const float inv = 127.0f / smx;   // gaussian row => smx > 0
  int4 o;
  o.x = pack4(v[0].x, v[0].y, v[0].z, v[0].w, inv);
  o.y = pack4(v[1].x, v[1].y, v[1].z, v[1].w, inv);
  o.z = pack4(v[2].x, v[2].y, v[2].z, v[2].w, inv);
  o.w = pack4(v[3].x, v[3].y, v[3].z, v[3].w, inv);
  xq[(size_t)row * (D_IN / 16) + t] = o;
}

// ---- kernel 2: per-row L2 norm (fp64 accum) + quantize W -> int8 q ----
// q = rint(clip(W/(norm+1e-8), -1, 1) * 127),  sn[row] = norm/127
__global__ void quant_w_kernel(const float* __restrict__ W, int4* __restrict__ wq,
                               float* __restrict__ sn) {
  const int row = blockIdx.x;
  const int t = threadIdx.x;
  const float* wr = W + (size_t)row * D_IN;

  float4 v[4];
  double ss = 0.0;
#pragma unroll
  for (int j = 0; j < 4; j++) {
    v[j] = ((const float4*)wr)[t * 4 + j];
    ss += (double)v[j].x * v[j].x + (double)v[j].y * v[j].y +
          (double)v[j].z * v[j].z + (double)v[j].w * v[j].w;
  }
#pragma unroll
  for (int off = 32; off; off >>= 1) ss += __shfl_down(ss, off);
  __shared__ double red[4];
  __shared__ float shn;
  if ((t & 63) == 0) red[t >> 6] = ss;
  __syncthreads();
  if (t == 0) {
    double tot = red[0] + red[1] + red[2] + red[3];
    float nrm = (float)sqrt(tot);
    shn = nrm;
    sn[row] = nrm * (1.0f / 127.0f);
  }
  __syncthreads();

  const float den = shn + 1e-8f;
  int4 o;
  int* op = (int*)&o;
#pragma unroll
  for (int j = 0; j < 4; j++) {
    float e[4] = {v[j].x, v[j].y, v[j].z, v[j].w};
    int q[4];
#pragma unroll
    for (int c = 0; c < 4; c++) {
      float wn = e[c] / den;
      wn = fminf(1.0f, fmaxf(-1.0f, wn));
      q[c] = (int)rintf(wn * 127.0f) & 255;
    }
    op[j] = q[0] | (q[1] << 8) | (q[2] << 16) | (q[3] << 24);
  }
  wq[(size_t)row * (D_IN / 16) + t] = o;
}

// ---- kernel 3: int8 GEMM, C[M,N] = A[M,K] @ B[N,K]^T (int32 acc),
// epilogue C = acc * sx[m] * sn[n] + bias[n].
// 128x128 tile, BK=64, 256 threads = 4 waves (2x2), each wave 64x64 via
// 4x4 grid of mfma_i32_16x16x64_i8. global_load_lds 16B staging with
// XOR-swizzled source chunks (kc ^ (row&3)) to kill ds_read bank conflicts.
__global__ void gemm_i8_kernel(const char* __restrict__ A, const char* __restrict__ B,
                               const float* __restrict__ sx, const float* __restrict__ sn,
                               const float* __restrict__ bias, float* __restrict__ C) {
  __shared__ __align__(16) char lds_a[128 * 64];
  __shared__ __align__(16) char lds_b[128 * 64];

  const int t = threadIdx.x;
  const int lane = t & 63;
  const int wave = t >> 6;
  const int wm = wave >> 1, wn = wave & 1;
  const int m0 = blockIdx.y * 128;
  const int n0 = blockIdx.x * 128;

  // staging: thread t -> LDS chunk t (round 0) and t+256 (round 1, +64 rows).
  // LDS[row][kc] holds global chunk (kc ^ (row&3)); row&3 invariant under +64.
  const int srow = t >> 2;
  const int skc = (t & 3) ^ (srow & 3);
  const char* gA = A + (size_t)(m0 + srow) * D_IN + skc * 16;
  const char* gB = B + (size_t)(n0 + srow) * D_IN + skc * 16;
  char* lA = lds_a + t * 16;
  char* lB = lds_b + t * 16;
  const size_t rstride = (size_t)64 * D_IN;

  // fragment: A[m = lane&15][k = (lane>>4)*16 + j], j in [0,16) -> one b128.
  // swizzled location: row*64 + ((g ^ (row&3))*16); row&3 == ml&3 for all mi.
  const int ml = lane & 15;
  const int g = lane >> 4;
  const int xorb = (g ^ (ml & 3)) * 16;
  const char* ra = lds_a + (wm * 64 + ml) * 64 + xorb;
  const char* rb = lds_b + (wn * 64 + ml) * 64 + xorb;

  i32x4 acc[4][4];
#pragma unroll
  for (int i = 0; i < 4; i++)
#pragma unroll
    for (int j = 0; j < 4; j++) acc[i][j] = (i32x4)0;

  for (int k0 = 0; k0 < D_IN; k0 += 64) {
    async16(gA, lA);
    async16(gA + rstride, lA + 4096);
    async16(gB, lB);
    async16(gB + rstride, lB + 4096);
    gA += 64; gB += 64;
    __syncthreads();   // drains vmcnt -> tiles ready

    i32x4 af[4], bfr[4];
#pragma unroll
    for (int i = 0; i < 4; i++) {
      af[i]  = *(const i32x4*)(ra + i * 16 * 64);
      bfr[i] = *(const i32x4*)(rb + i * 16 * 64);
    }
#pragma unroll
    for (int mi = 0; mi < 4; mi++)
#pragma unroll
      for (int ni = 0; ni < 4; ni++)
        acc[mi][ni] = __builtin_amdgcn_mfma_i32_16x16x64_i8(af[mi], bfr[ni], acc[mi][ni], 0, 0, 0);
    __syncthreads();   // before next staging overwrites LDS
  }

  // epilogue: D col = lane&15 (n), row = (lane>>4)*4 + reg (m)
  float scn[4], bsv[4];
#pragma unroll
  for (int ni = 0; ni < 4; ni++) {
    const int col = n0 + wn * 64 + ni * 16 + ml;
    scn[ni] = sn[col];
    bsv[ni] = bias[col];
  }
#pragma unroll
  for (int mi = 0; mi < 4; mi++) {
    const int rbase = m0 + wm * 64 + mi * 16 + g * 4;
    float sxv[4];
#pragma unroll
    for (int r = 0; r < 4; r++) sxv[r] = sx[rbase + r];
#pragma unroll
    for (int ni = 0; ni < 4; ni++) {
      const int col = n0 + wn * 64 + ni * 16 + ml;
#pragma unroll
      for (int r = 0; r < 4; r++)
        C[(size_t)(rbase + r) * D_OUT + col] =
            (float)acc[mi][ni][r] * (sxv[r] * scn[ni]) + bsv[ni];
    }
  }
}

extern "C" void kernel_launch(void* const* d_in, const int* in_sizes, int n_in,
                              void* d_out, int out_size, void* d_ws, size_t ws_size,
                              hipStream_t stream) {
  const float* x    = (const float*)d_in[0];   // [4,2048,4096]
  const float* W    = (const float*)d_in[1];   // [4096,4096]
  const float* bias = (const float*)d_in[2];   // [4096]
  float* out = (float*)d_out;                  // [4,2048,4096]

  char* ws = (char*)d_ws;
  char*  xq = ws;                                             // 33.5 MB int8
  char*  wq = ws + (size_t)M_TOT * D_IN;                      // 16.8 MB int8
  float* sx = (float*)(wq + (size_t)D_OUT * D_IN);            // 32 KB
  float* sn = sx + M_TOT;                                     // 16 KB

  quant_x_kernel<<<M_TOT, 256, 0, stream>>>(x, (int4*)xq, sx);
  quant_w_kernel<<<D_OUT, 256, 0, stream>>>(W, (int4*)wq, sn);
  dim3 grid(D_OUT / 128, M_TOT / 128);   // (32, 64)
  gemm_i8_kernel<<<grid, 256, 0, stream>>>(xq, wq, sx, sn, bias, out);
}

// Round 3
// 405.363 us; speedup vs baseline: 1.3851x; 1.0369x over previous
//
#include <hip/hip_runtime.h>
#include <hip/hip_bf16.h>

typedef __attribute__((ext_vector_type(4))) int i32x4;
typedef __attribute__((address_space(3))) char lds3;

#define D_IN  4096
#define D_OUT 4096
#define M_TOT 8192
#define RSTRIDE ((size_t)64 * D_IN)   // +64 rows in int8 bytes

// ---- async 16B global->LDS (wave-uniform base + lane*16 dest semantics) ----
__device__ __forceinline__ void async16(const void* g, lds3* l) {
  __builtin_amdgcn_global_load_lds(
      (__attribute__((address_space(1))) void*)g,
      (__attribute__((address_space(3))) void*)l,
      16, 0, 0);
}

// ds_read_b128 via inline asm: invisible to the compiler's waitcnt pass, so no
// auto "s_waitcnt vmcnt(0)" is inserted against outstanding global_load_lds.
#define DSR(dst, addr, off) \
  asm volatile("ds_read_b128 %0, %1 offset:%2" : "=v"(dst) : "v"(addr), "i"(off))

__device__ __forceinline__ int pack4(float a, float b, float c, float d, float s) {
  int q0 = (int)rintf(a * s) & 255;
  int q1 = (int)rintf(b * s) & 255;
  int q2 = (int)rintf(c * s) & 255;
  int q3 = (int)rintf(d * s) & 255;
  return q0 | (q1 << 8) | (q2 << 16) | (q3 << 24);
}

// ---- kernel 1: per-row absmax quantize x -> int8, sx[row] = rowmax/127 ----
__global__ void quant_x_kernel(const float* __restrict__ x, int4* __restrict__ xq,
                               float* __restrict__ sx) {
  const int row = blockIdx.x;
  const int t = threadIdx.x;
  const float* xr = x + (size_t)row * D_IN;

  float4 v[4];
  float mx = 0.f;
#pragma unroll
  for (int j = 0; j < 4; j++) {
    v[j] = ((const float4*)xr)[t * 4 + j];
    mx = fmaxf(mx, fmaxf(fmaxf(fabsf(v[j].x), fabsf(v[j].y)),
                         fmaxf(fabsf(v[j].z), fabsf(v[j].w))));
  }
#pragma unroll
  for (int off = 32; off; off >>= 1) mx = fmaxf(mx, __shfl_down(mx, off));
  __shared__ float red[4];
  __shared__ float smx;
  if ((t & 63) == 0) red[t >> 6] = mx;
  __syncthreads();
  if (t == 0) {
    float m = fmaxf(fmaxf(red[0], red[1]), fmaxf(red[2], red[3]));
    smx = m;
    sx[row] = m * (1.0f / 127.0f);
  }
  __syncthreads();

  const float inv = 127.0f / smx;
  int4 o;
  o.x = pack4(v[0].x, v[0].y, v[0].z, v[0].w, inv);
  o.y = pack4(v[1].x, v[1].y, v[1].z, v[1].w, inv);
  o.z = pack4(v[2].x, v[2].y, v[2].z, v[2].w, inv);
  o.w = pack4(v[3].x, v[3].y, v[3].z, v[3].w, inv);
  xq[(size_t)row * (D_IN / 16) + t] = o;
}

// ---- kernel 2: per-row L2 norm (fp64 accum) + quantize W -> int8 q ----
__global__ void quant_w_kernel(const float* __restrict__ W, int4* __restrict__ wq,
                               float* __restrict__ sn) {
  const int row = blockIdx.x;
  const int t = threadIdx.x;
  const float* wr = W + (size_t)row * D_IN;

  float4 v[4];
  double ss = 0.0;
#pragma unroll
  for (int j = 0; j < 4; j++) {
    v[j] = ((const float4*)wr)[t * 4 + j];
    ss += (double)v[j].x * v[j].x + (double)v[j].y * v[j].y +
          (double)v[j].z * v[j].z + (double)v[j].w * v[j].w;
  }
#pragma unroll
  for (int off = 32; off; off >>= 1) ss += __shfl_down(ss, off);
  __shared__ double red[4];
  __shared__ float shn;
  if ((t & 63) == 0) red[t >> 6] = ss;
  __syncthreads();
  if (t == 0) {
    double tot = red[0] + red[1] + red[2] + red[3];
    float nrm = (float)sqrt(tot);
    shn = nrm;
    sn[row] = nrm * (1.0f / 127.0f);
  }
  __syncthreads();

  const float den = shn + 1e-8f;
  int4 o;
  int* op = (int*)&o;
#pragma unroll
  for (int j = 0; j < 4; j++) {
    float e[4] = {v[j].x, v[j].y, v[j].z, v[j].w};
    int q[4];
#pragma unroll
    for (int c = 0; c < 4; c++) {
      float wn = e[c] / den;
      wn = fminf(1.0f, fmaxf(-1.0f, wn));
      q[c] = (int)rintf(wn * 127.0f) & 255;
    }
    op[j] = q[0] | (q[1] << 8) | (q[2] << 16) | (q[3] << 24);
  }
  wq[(size_t)row * (D_IN / 16) + t] = o;
}

// ---- GEMM K-loop iteration, 3-stage pipeline ----
// S = read stage; VM = vmcnt to wait (4 in steady state, 0 at tail);
// ISSUE = whether to prefetch stage (S+2)%3 (pointers passed by caller).
template<int S, int VM, bool ISSUE>
__device__ __forceinline__ void k_iter(unsigned aA, unsigned aB,
                                       const char* pA, const char* pB,
                                       lds3* lA, lds3* lB,
                                       i32x4 (&acc)[4][4]) {
  asm volatile("s_waitcnt vmcnt(%0)" :: "i"(VM));            // stage S loads done
  asm volatile("s_barrier" ::: "memory");                    // all waves: S ready, prev reads done
  if (ISSUE) {                                               // prefetch -> stage (S+2)%3
    async16(pA, lA);
    async16(pA + RSTRIDE, lA + 4096);
    async16(pB, lB);
    async16(pB + RSTRIDE, lB + 4096);
  }
  i32x4 af[4], bf[4];
  DSR(af[0], aA, S * 16384 + 0);
  DSR(af[1], aA, S * 16384 + 1024);
  DSR(af[2], aA, S * 16384 + 2048);
  DSR(af[3], aA, S * 16384 + 3072);
  DSR(bf[0], aB, S * 16384 + 8192 + 0);
  DSR(bf[1], aB, S * 16384 + 8192 + 1024);
  DSR(bf[2], aB, S * 16384 + 8192 + 2048);
  DSR(bf[3], aB, S * 16384 + 8192 + 3072);
  // tie frags through the wait so MFMAs can't be scheduled before data lands
  asm volatile("s_waitcnt lgkmcnt(0)"
               : "+v"(af[0]), "+v"(af[1]), "+v"(af[2]), "+v"(af[3]),
                 "+v"(bf[0]), "+v"(bf[1]), "+v"(bf[2]), "+v"(bf[3]));
#pragma unroll
  for (int mi = 0; mi < 4; mi++)
#pragma unroll
    for (int ni = 0; ni < 4; ni++)
      acc[mi][ni] = __builtin_amdgcn_mfma_i32_16x16x64_i8(af[mi], bf[ni], acc[mi][ni], 0, 0, 0);
}

// ---- kernel 3: int8 GEMM, C = A @ B^T, epilogue acc*sx[m]*sn[n] + bias[n] ----
// 128x128 tile, BK=64, 4 waves (2x2, 64x64 each), 3-stage software pipeline,
// one s_barrier/iter, vmcnt never drained to 0 until the tail.
__global__ __launch_bounds__(256, 3)
void gemm_i8_kernel(const char* __restrict__ A, const char* __restrict__ B,
                    const float* __restrict__ sx, const float* __restrict__ sn,
                    const float* __restrict__ bias, float* __restrict__ C) {
  __shared__ __align__(16) char smem[3 * 16384];   // stage: A 8KB | B 8KB

  const int t = threadIdx.x;
  const int lane = t & 63;
  const int wave = t >> 6;
  const int wm = wave >> 1, wn = wave & 1;
  const int m0 = blockIdx.y * 128;
  const int n0 = blockIdx.x * 128;

  // staging: thread t fills 16B chunk t (rows 0-63) and t+256 (rows 64-127).
  // LDS slot (row, c) holds global chunk q = (c - ((row&15)>>1)) & 3 so that
  // reads land 2 lanes per bank-class per 16-lane quarter.
  const int srow = t >> 2;
  const int q = ((t & 3) - ((srow & 15) >> 1)) & 3;
  const char* gA = A + (size_t)(m0 + srow) * D_IN + q * 16;
  const char* gB = B + (size_t)(n0 + srow) * D_IN + q * 16;

  lds3* l3 = (lds3*)smem;
  lds3* lA0 = l3 + t * 16;            // stage s: + s*16384
  lds3* lB0 = l3 + 8192 + t * 16;

  // fragment read addresses: lane (ml, g) reads A[row=wX*64+mi*16+ml][k-chunk g]
  // at slot column c = (g + (ml>>1)) & 3; stage/mi offsets via immediates.
  const int ml = lane & 15;
  const int g = lane >> 4;
  const unsigned cperm = (unsigned)((g + (ml >> 1)) & 3);
  const unsigned lds_base = (unsigned)(size_t)l3;
  const unsigned aA = lds_base + (wm * 64 + ml) * 64 + cperm * 16;
  const unsigned aB = lds_base + (wn * 64 + ml) * 64 + cperm * 16;

  i32x4 acc[4][4];
#pragma unroll
  for (int i = 0; i < 4; i++)
#pragma unroll
    for (int j = 0; j < 4; j++) acc[i][j] = (i32x4)0;

  // prologue: stage0 (k=0), stage1 (k=64)
  async16(gA, lA0);            async16(gA + RSTRIDE, lA0 + 4096);
  async16(gB, lB0);            async16(gB + RSTRIDE, lB0 + 4096);
  async16(gA + 64, lA0 + 16384);           async16(gA + 64 + RSTRIDE, lA0 + 16384 + 4096);
  async16(gB + 64, lB0 + 16384);           async16(gB + 64 + RSTRIDE, lB0 + 16384 + 4096);

  const char* pA = gA + 128;   // k column for the next issue: (i+2)*64 at i=0
  const char* pB = gB + 128;

#pragma unroll 1
  for (int tr = 0; tr < 20; ++tr) {      // iters 0..59
    k_iter<0, 4, true>(aA, aB, pA, pB, lA0 + 32768, lB0 + 32768, acc); pA += 64; pB += 64;
    k_iter<1, 4, true>(aA, aB, pA, pB, lA0,         lB0,         acc); pA += 64; pB += 64;
    k_iter<2, 4, true>(aA, aB, pA, pB, lA0 + 16384, lB0 + 16384, acc); pA += 64; pB += 64;
  }
  // iters 60..63
  k_iter<0, 4, true >(aA, aB, pA, pB, lA0 + 32768, lB0 + 32768, acc); pA += 64; pB += 64;
  k_iter<1, 4, true >(aA, aB, pA, pB, lA0,         lB0,         acc);
  k_iter<2, 4, false>(aA, aB, pA, pB, lA0,         lB0,         acc);
  k_iter<0, 0, false>(aA, aB, pA, pB, lA0,         lB0,         acc);

  // epilogue: D col = lane&15 (n), row = (lane>>4)*4 + reg (m)
  float scn[4], bsv[4];
#pragma unroll
  for (int ni = 0; ni < 4; ni++) {
    const int col = n0 + wn * 64 + ni * 16 + ml;
    scn[ni] = sn[col];
    bsv[ni] = bias[col];
  }
#pragma unroll
  for (int mi = 0; mi < 4; mi++) {
    const int rbase = m0 + wm * 64 + mi * 16 + g * 4;
    float sxv[4];
#pragma unroll
    for (int r = 0; r < 4; r++) sxv[r] = sx[rbase + r];
#pragma unroll
    for (int ni = 0; ni < 4; ni++) {
      const int col = n0 + wn * 64 + ni * 16 + ml;
#pragma unroll
      for (int r = 0; r < 4; r++)
        C[(size_t)(rbase + r) * D_OUT + col] =
            (float)acc[mi][ni][r] * (sxv[r] * scn[ni]) + bsv[ni];
    }
  }
}

extern "C" void kernel_launch(void* const* d_in, const int* in_sizes, int n_in,
                              void* d_out, int out_size, void* d_ws, size_t ws_size,
                              hipStream_t stream) {
  const float* x    = (const float*)d_in[0];   // [4,2048,4096]
  const float* W    = (const float*)d_in[1];   // [4096,4096]
  const float* bias = (const float*)d_in[2];   // [4096]
  float* out = (float*)d_out;                  // [4,2048,4096]

  char* ws = (char*)d_ws;
  char*  xq = ws;                                             // 33.5 MB int8
  char*  wq = ws + (size_t)M_TOT * D_IN;                      // 16.8 MB int8
  float* sx = (float*)(wq + (size_t)D_OUT * D_IN);
  float* sn = sx + M_TOT;

  quant_x_kernel<<<M_TOT, 256, 0, stream>>>(x, (int4*)xq, sx);
  quant_w_kernel<<<D_OUT, 256, 0, stream>>>(W, (int4*)wq, sn);
  dim3 grid(D_OUT / 128, M_TOT / 128);   // (32, 64)
  gemm_i8_kernel<<<grid, 256, 0, stream>>>(xq, wq, sx, sn, bias, out);
}